// Round 4
// baseline (865.519 us; speedup 1.0000x reference)
//
#include <hip/hip_runtime.h>
#include <math.h>

namespace {

constexpr int kB   = 8;
constexpr int kT   = 661500;   // input samples per channel
constexpr int kHop = 256;
constexpr int kNF  = 513;      // freq bins
constexpr int kNT  = 2584;     // frames: 1 + 661500/256
constexpr size_t kFT    = (size_t)kNF * kNT;       // 1,325,592 floats per (b,c) chunk
constexpr size_t kPlane = (size_t)kB * kFT;        // 10,604,736 floats

// Staging scheme (race-free, in-place in d_out):
//   Output chunk index ci = b*6 + c holds final (f,t) data for (b, channel c).
//   k_stft stages channel c for batch b at chunk (b*6 + c + 1), (t,f) layout.
//   Transpose launch c reads residue-(c+1) chunks, writes residue-c chunks:
//     write residues (c) are disjoint from all unconsumed staging residues
//     (c+1 .. 5), and from this launch's own reads. k_psy writes residue-5
//     chunks last, after launch c=4 consumed them. Stream order serializes.
//   ws: mag_db plane (b,t,f) at ws[0 .. kPlane), spread S(513x513) at ws+kPlane.

__device__ __forceinline__ int swz(int i) { return i ^ ((i >> 5) & 31); }

// ---------------- STFT + per-frame features ----------------
__global__ __launch_bounds__(256) void k_stft(const float* __restrict__ x,
                                              float* __restrict__ out,
                                              float* __restrict__ ws) {
  const int t = blockIdx.x;
  const int b = blockIdx.y;
  const int tid = threadIdx.x;
  __shared__ float sre[1024];
  __shared__ float sim[1024];
  __shared__ float twr[512];
  __shared__ float twi[512];
  __shared__ float mags[kNF];
  __shared__ float d2[256];
  __shared__ float d3[171];

  // twiddles: exp(-2*pi*i*j/1024)
  for (int j = tid; j < 512; j += 256) {
    float s, c;
    sincospif((float)j * (1.0f / 512.0f), &s, &c);
    twr[j] = c;
    twi[j] = -s;
  }

  // load frame (reflect pad), window, pack L + i*R, bit-reversed store
  const float* xb = x + (size_t)b * 2 * kT;
  const float c2pi = 6.28318548202514648f;  // fl(2*pi) as float32, matches jnp
#pragma unroll
  for (int q = 0; q < 4; ++q) {
    int n = tid + q * 256;
    int g = t * kHop + n - 512;
    g = (g < 0) ? -g : g;
    g = (g >= kT) ? (2 * kT - 2 - g) : g;
    float arg = ((float)n * c2pi) * (1.0f / 1024.0f);
    float wv = 0.5f * (1.0f - cosf(arg));
    float l = xb[g] * wv;
    float r = xb[(size_t)kT + g] * wv;
    int rv = (int)(__brev((unsigned)n) >> 22);
    int rs = swz(rv);
    sre[rs] = l;
    sim[rs] = r;
  }
  __syncthreads();

  // radix-2 DIT FFT, 10 stages
#pragma unroll
  for (int s = 1; s <= 10; ++s) {
    const int half = 1 << (s - 1);
#pragma unroll
    for (int jj = 0; jj < 2; ++jj) {
      int j = tid + jj * 256;
      int pos = j & (half - 1);
      int i0 = ((j >> (s - 1)) << s) + pos;
      int i1 = i0 + half;
      int ti = pos << (10 - s);
      float wr = twr[ti], wi = twi[ti];
      int a0 = swz(i0), a1 = swz(i1);
      float xr = sre[a1], xi = sim[a1];
      float br = xr * wr - xi * wi;
      float bi = xr * wi + xi * wr;
      float cr = sre[a0], ci = sim[a0];
      sre[a0] = cr + br; sim[a0] = ci + bi;
      sre[a1] = cr - br; sim[a1] = ci - bi;
    }
    __syncthreads();
  }

  // staging: channel c for this batch at chunk (b*6 + c + 1), (t,f) layout
  float* outb = out + (size_t)b * 6 * kFT;
  const size_t row = (size_t)t * kNF;
  float* pre = outb + 1 * kFT + row;
  float* pim = outb + 2 * kFT + row;
  float* phm = outb + 3 * kFT + row;
  float* pip = outb + 4 * kFT + row;
  float* ppn = outb + 5 * kFT + row;
  float* pdb = ws + ((size_t)b * kNT + t) * kNF;  // mag_db plane in scratch

  // unpack packed FFT -> spec_l, spec_r; per-bin features
  for (int k = tid; k < kNF; k += 256) {
    int k2 = (1024 - k) & 1023;
    float a = sre[swz(k)], bb = sim[swz(k)];
    float c = sre[swz(k2)], d = sim[swz(k2)];
    float Lre = 0.5f * (a + c), Lim = 0.5f * (bb - d);
    float Rre = 0.5f * (bb + d), Rim = 0.5f * (c - a);
    float sr = 0.5f * (Lre + Rre), si = 0.5f * (Lim + Rim);
    float mg = sqrtf(sr * sr + si * si);
    mags[k] = mg;
    float ipd = atan2f(Lim, Lre) - atan2f(Rim, Rre);
    float el = Lre * Lre + Lim * Lim;
    float er = Rre * Rre + Rim * Rim;
    float pan = (el - er) / (el + er + 1e-10f);
    float mm = fmaxf(mg, 1e-10f);
    float db = 20.0f * log10f(mm);
    db = fminf(fmaxf(db, -100.0f), 0.0f);
    pre[k] = sr;
    pim[k] = si;
    pip[k] = ipd;
    ppn[k] = pan;
    pdb[k] = (db + 100.0f) * 0.01f;
  }
  __syncthreads();

  // harmonic plane: downsample to 256 and 171 (exact reference arithmetic)
  {
    int j = tid;
    float src = __fsub_rn(__fmul_rn((float)j + 0.5f, 513.0f / 256.0f), 0.5f);
    src = fminf(fmaxf(src, 0.0f), 512.0f);
    int i0 = (int)src;
    int i1 = min(i0 + 1, 512);
    float w = src - (float)i0;
    d2[j] = mags[i0] * (1.0f - w) + mags[i1] * w;
  }
  if (tid < 171) {
    int j = tid;
    float src = __fsub_rn(__fmul_rn((float)j + 0.5f, 3.0f), 0.5f);
    src = fminf(fmaxf(src, 0.0f), 512.0f);
    int i0 = (int)src;
    int i1 = min(i0 + 1, 512);
    float w = src - (float)i0;
    d3[j] = mags[i0] * (1.0f - w) + mags[i1] * w;
  }
  __syncthreads();

  // upsample back; combine exactly as reference: expm1(sum of log1p)
  for (int k = tid; k < kNF; k += 256) {
    float s2 = __fsub_rn(__fmul_rn((float)k + 0.5f, 256.0f / 513.0f), 0.5f);
    s2 = fminf(fmaxf(s2, 0.0f), 255.0f);
    int a0 = (int)s2;
    int a1 = min(a0 + 1, 255);
    float w2 = s2 - (float)a0;
    float u2 = d2[a0] * (1.0f - w2) + d2[a1] * w2;

    float s3 = __fsub_rn(__fmul_rn((float)k + 0.5f, 171.0f / 513.0f), 0.5f);
    s3 = fminf(fmaxf(s3, 0.0f), 170.0f);
    int c0 = (int)s3;
    int c1 = min(c0 + 1, 170);
    float w3 = s3 - (float)c0;
    float u3 = d3[c0] * (1.0f - w3) + d3[c1] * w3;

    float hs = log1pf(mags[k]) + log1pf(u2) + log1pf(u3);
    phm[k] = expm1f(hs);
  }
}

// -------- transpose channel c: chunk (b*6+c+1) (t,f) -> chunk (b*6+c) (f,t) --------
__global__ __launch_bounds__(256) void k_transpose(float* __restrict__ out, int c) {
  __shared__ float tile[64][65];
  const int t0 = blockIdx.x * 64;
  const int f0 = blockIdx.y * 64;
  const int b = blockIdx.z;
  const float* src = out + ((size_t)b * 6 + (c + 1)) * kFT;
  float* dst = out + ((size_t)b * 6 + c) * kFT;
  for (int i = threadIdx.x; i < 4096; i += 256) {
    int tl = i >> 6, fl = i & 63;
    int t = t0 + tl, f = f0 + fl;
    float v = 0.0f;
    if (t < kNT && f < kNF) v = src[(size_t)t * kNF + f];
    tile[fl][tl] = v;
  }
  __syncthreads();
  for (int i = threadIdx.x; i < 4096; i += 256) {
    int fl = i >> 6, tl = i & 63;
    int t = t0 + tl, f = f0 + fl;
    if (t < kNT && f < kNF)
      dst[(size_t)f * kNT + t] = tile[fl][tl];
  }
}

// ---------------- spread matrix S (513x513) at ws + kPlane ----------------
__global__ __launch_bounds__(256) void k_spread(float* __restrict__ ws) {
  __shared__ float bark[kNF];
  __shared__ float red[256];
  const int f = blockIdx.x;
  const int tid = threadIdx.x;
  float* S = ws + kPlane;
  for (int g = tid; g < kNF; g += 256) {
    float fr = (float)g * (11025.0f / 512.0f);
    float r = fr * (1.0f / 7500.0f);
    bark[g] = 13.0f * atanf(0.00076f * fr) + 3.5f * atanf(r * r);
  }
  __syncthreads();
  float bf = bark[f];
  float partial = 0.0f;
  for (int g = tid; g < kNF; g += 256) {
    float d = fabsf(bf - bark[g]);
    float v = expf(-2.8f * d * d);   // == exp(-0.7*(d/0.5)^2); both ==1 at d==0
    S[(size_t)f * kNF + g] = v;
    partial += v;
  }
  red[tid] = partial;
  __syncthreads();
  for (int off = 128; off > 0; off >>= 1) {
    if (tid < off) red[tid] += red[tid + off];
    __syncthreads();
  }
  float inv = 1.0f / (red[0] + 1e-8f);
  for (int g = tid; g < kNF; g += 256) S[(size_t)f * kNF + g] *= inv;
}

// ------- masking GEMM: out ch5 = clip(S @ mdb - 0.12, 0, 1), fp32 -------
__global__ __launch_bounds__(256) void k_psy(const float* __restrict__ ws,
                                             float* __restrict__ out) {
  __shared__ float Sl[16][132];
  __shared__ float Dl[16][132];
  const int t0 = blockIdx.x * 128;
  const int f0 = blockIdx.y * 128;
  const int b = blockIdx.z;
  const float* S = ws + kPlane;                       // spread matrix
  const float* D = ws + (size_t)b * kNT * kNF;        // mdb (b,t,f)
  const int tid = threadIdx.x;
  const int fr = (tid & 15) * 8;
  const int tc = (tid >> 4) * 8;
  float acc[8][8] = {};
  for (int k0 = 0; k0 < kNF; k0 += 16) {
    for (int i = tid; i < 2048; i += 256) {
      int r = i >> 4, c = i & 15;
      int f = f0 + r, g = k0 + c;
      float v = 0.0f;
      if (f < kNF && g < kNF) v = S[(size_t)f * kNF + g];
      Sl[c][r] = v;
    }
    for (int i = tid; i < 2048; i += 256) {
      int r = i >> 4, c = i & 15;
      int t = t0 + r, g = k0 + c;
      float v = 0.0f;
      if (t < kNT && g < kNF) v = D[(size_t)t * kNF + g];
      Dl[c][r] = v;
    }
    __syncthreads();
#pragma unroll
    for (int kk = 0; kk < 16; ++kk) {
      float a[8], bb[8];
#pragma unroll
      for (int i = 0; i < 8; ++i) a[i] = Sl[kk][fr + i];
#pragma unroll
      for (int j = 0; j < 8; ++j) bb[j] = Dl[kk][tc + j];
#pragma unroll
      for (int i = 0; i < 8; ++i)
#pragma unroll
        for (int j = 0; j < 8; ++j) acc[i][j] = fmaf(a[i], bb[j], acc[i][j]);
    }
    __syncthreads();
  }
#pragma unroll
  for (int i = 0; i < 8; ++i) {
    int f = f0 + fr + i;
    if (f >= kNF) break;
#pragma unroll
    for (int j = 0; j < 8; ++j) {
      int t = t0 + tc + j;
      if (t < kNT) {
        float v = acc[i][j] - 0.12f;
        v = fminf(fmaxf(v, 0.0f), 1.0f);
        out[(((size_t)b * 6 + 5) * kFT) + (size_t)f * kNT + t] = v;
      }
    }
  }
}

}  // namespace

extern "C" void kernel_launch(void* const* d_in, const int* in_sizes, int n_in,
                              void* d_out, int out_size, void* d_ws, size_t ws_size,
                              hipStream_t stream) {
  const float* x = (const float*)d_in[0];
  float* out = (float*)d_out;
  float* ws = (float*)d_ws;

  // spread matrix (independent of STFT)
  hipLaunchKernelGGL(k_spread, dim3(kNF), dim3(256), 0, stream, ws);
  // STFT + features: stage ch c at chunk (b*6+c+1), mdb in ws
  hipLaunchKernelGGL(k_stft, dim3(kNT, kB), dim3(256), 0, stream, x, out, ws);
  // transpose chain: launch c reads residue-(c+1) chunks, writes residue-c.
  for (int c = 0; c < 5; ++c) {
    hipLaunchKernelGGL(k_transpose, dim3((kNT + 63) / 64, (kNF + 63) / 64, kB),
                       dim3(256), 0, stream, out, c);
  }
  // masking GEMM -> channel 5 (consumes ws, writes residue-5 chunks)
  hipLaunchKernelGGL(k_psy, dim3((kNT + 127) / 128, (kNF + 127) / 128, kB),
                     dim3(256), 0, stream, ws, out);
}

// Round 7
// 657.426 us; speedup vs baseline: 1.3165x; 1.3165x over previous
//
#include <hip/hip_runtime.h>
#include <math.h>

namespace {

constexpr int kB   = 8;
constexpr int kT   = 661500;   // input samples per channel
constexpr int kHop = 256;
constexpr int kNF  = 513;      // freq bins
constexpr int kNT  = 2584;     // frames: 1 + 661500/256
constexpr int kKP  = 544;      // K padded to 17*32 for MFMA
constexpr int kFP  = 576;      // f padded to 9*64 for MFMA A-tiles
constexpr size_t kFT = (size_t)kNF * kNT;   // floats per (b,c) output chunk

// ws layout (bytes):
//   Db  (bf16 mag_db, [8][2584][544], g zero-padded)  at 0          (22,493,696 B)
//   Sb  (bf16 spread, [576][544], zero-padded)        at kDbBytes   (   626,688 B)
//   Cst (f32: twr[512], twi[512], win[1024])          at kCstBytes  (     8,192 B)
constexpr size_t kDbBytes  = (size_t)kB * kNT * kKP * 2;
constexpr size_t kSbBytes  = (size_t)kFP * kKP * 2;
constexpr size_t kCstBytes = kDbBytes + kSbBytes;
typedef __attribute__((ext_vector_type(8))) short bf16x8;
typedef __attribute__((ext_vector_type(4))) float f32x4;

__device__ __forceinline__ int swz(int i) { return i ^ ((i >> 5) & 31); }

__device__ __forceinline__ ushort f2bf(float x) {  // RNE float->bf16
  unsigned u = __float_as_uint(x);
  return (ushort)((u + 0x7FFFu + ((u >> 16) & 1u)) >> 16);
}

// ---------------- constant tables (twiddles + hann window) ----------------
__global__ __launch_bounds__(256) void k_const(float* __restrict__ cst) {
  const int tid = threadIdx.x;
  for (int j = tid; j < 512; j += 256) {   // exp(-2*pi*i*j/1024)
    float s, c;
    sincospif((float)j * (1.0f / 512.0f), &s, &c);
    cst[j] = c;
    cst[512 + j] = -s;
  }
  const float c2pi = 6.28318548202514648f;  // fl(2*pi) as float32, matches jnp
  for (int n = tid; n < 1024; n += 256) {
    float arg = ((float)n * c2pi) * (1.0f / 1024.0f);
    cst[1024 + n] = 0.5f * (1.0f - cosf(arg));
  }
}

// ---------------- STFT + per-frame features ----------------
__global__ __launch_bounds__(256) void k_stft(const float* __restrict__ x,
                                              float* __restrict__ out,
                                              ushort* __restrict__ Db,
                                              const float* __restrict__ cst) {
  const int t = blockIdx.x;
  const int b = blockIdx.y;
  const int tid = threadIdx.x;
  __shared__ float sre[1024];
  __shared__ float sim[1024];
  __shared__ float twr[512];
  __shared__ float twi[512];
  __shared__ float mags[kNF];
  __shared__ float d2[256];
  __shared__ float d3[171];

  // twiddles from table
  for (int j = tid; j < 512; j += 256) {
    twr[j] = cst[j];
    twi[j] = cst[512 + j];
  }

  // load frame (reflect pad), window from table, pack L + i*R, bit-rev store
  const float* wtb = cst + 1024;
  const float* xb = x + (size_t)b * 2 * kT;
  const int start = t * kHop - 512;
  if (t >= 2 && t < kNT - 1) {
    // interior frame: contiguous & 16B-aligned (start = 256t-512, mult of 4)
    const float4 l4 = ((const float4*)(xb + start))[tid];
    const float4 r4 = ((const float4*)(xb + kT + start))[tid];
    const float4 w4 = ((const float4*)wtb)[tid];
    float lv[4] = {l4.x * w4.x, l4.y * w4.y, l4.z * w4.z, l4.w * w4.w};
    float rw[4] = {r4.x * w4.x, r4.y * w4.y, r4.z * w4.z, r4.w * w4.w};
#pragma unroll
    for (int e = 0; e < 4; ++e) {
      int n = tid * 4 + e;
      int rv = (int)(__brev((unsigned)n) >> 22);
      int rs = swz(rv);
      sre[rs] = lv[e];
      sim[rs] = rw[e];
    }
  } else {
    // edge frame: scalar reflect path (t in {0,1,kNT-1})
#pragma unroll
    for (int q = 0; q < 4; ++q) {
      int n = tid + q * 256;
      int g = start + n;
      g = (g < 0) ? -g : g;
      g = (g >= kT) ? (2 * kT - 2 - g) : g;
      float wv = wtb[n];
      float l = xb[g] * wv;
      float r = xb[(size_t)kT + g] * wv;
      int rv = (int)(__brev((unsigned)n) >> 22);
      int rs = swz(rv);
      sre[rs] = l;
      sim[rs] = r;
    }
  }
  __syncthreads();

  // radix-2 DIT FFT, 10 stages
#pragma unroll
  for (int s = 1; s <= 10; ++s) {
    const int half = 1 << (s - 1);
#pragma unroll
    for (int jj = 0; jj < 2; ++jj) {
      int j = tid + jj * 256;
      int pos = j & (half - 1);
      int i0 = ((j >> (s - 1)) << s) + pos;
      int i1 = i0 + half;
      int ti = pos << (10 - s);
      float wr = twr[ti], wi = twi[ti];
      int a0 = swz(i0), a1 = swz(i1);
      float xr = sre[a1], xi = sim[a1];
      float br = xr * wr - xi * wi;
      float bi = xr * wi + xi * wr;
      float cr = sre[a0], ci = sim[a0];
      sre[a0] = cr + br; sim[a0] = ci + bi;
      sre[a1] = cr - br; sim[a1] = ci - bi;
    }
    __syncthreads();
  }

  // staging: channel c for this batch at chunk (b*6 + c + 1), (t,f) layout
  float* outb = out + (size_t)b * 6 * kFT;
  const size_t row = (size_t)t * kNF;
  float* pre = outb + 1 * kFT + row;
  float* pim = outb + 2 * kFT + row;
  float* phm = outb + 3 * kFT + row;
  float* pip = outb + 4 * kFT + row;
  float* ppn = outb + 5 * kFT + row;
  ushort* pdb = Db + ((size_t)b * kNT + t) * kKP;  // bf16 mag_db row

  // unpack packed FFT -> spec_l, spec_r; per-bin features
  for (int k = tid; k < kNF; k += 256) {
    int k2 = (1024 - k) & 1023;
    float a = sre[swz(k)], bb = sim[swz(k)];
    float c = sre[swz(k2)], d = sim[swz(k2)];
    float Lre = 0.5f * (a + c), Lim = 0.5f * (bb - d);
    float Rre = 0.5f * (bb + d), Rim = 0.5f * (c - a);
    float sr = 0.5f * (Lre + Rre), si = 0.5f * (Lim + Rim);
    float mg = sqrtf(sr * sr + si * si);
    mags[k] = mg;
    float ipd = atan2f(Lim, Lre) - atan2f(Rim, Rre);
    float el = Lre * Lre + Lim * Lim;
    float er = Rre * Rre + Rim * Rim;
    float pan = (el - er) / (el + er + 1e-10f);
    float mm = fmaxf(mg, 1e-10f);
    float db = 20.0f * log10f(mm);
    db = fminf(fmaxf(db, -100.0f), 0.0f);
    pre[k] = sr;
    pim[k] = si;
    pip[k] = ipd;
    ppn[k] = pan;
    pdb[k] = f2bf((db + 100.0f) * 0.01f);
  }
  // zero the K-pad of this Db row
  for (int k = kNF + tid; k < kKP; k += 256) pdb[k] = 0;
  __syncthreads();

  // harmonic plane: downsample to 256 and 171 (exact reference arithmetic)
  {
    int j = tid;
    float src = __fsub_rn(__fmul_rn((float)j + 0.5f, 513.0f / 256.0f), 0.5f);
    src = fminf(fmaxf(src, 0.0f), 512.0f);
    int i0 = (int)src;
    int i1 = min(i0 + 1, 512);
    float w = src - (float)i0;
    d2[j] = mags[i0] * (1.0f - w) + mags[i1] * w;
  }
  if (tid < 171) {
    int j = tid;
    float src = __fsub_rn(__fmul_rn((float)j + 0.5f, 3.0f), 0.5f);
    src = fminf(fmaxf(src, 0.0f), 512.0f);
    int i0 = (int)src;
    int i1 = min(i0 + 1, 512);
    float w = src - (float)i0;
    d3[j] = mags[i0] * (1.0f - w) + mags[i1] * w;
  }
  __syncthreads();

  // upsample back; combine exactly as reference: expm1(sum of log1p)
  for (int k = tid; k < kNF; k += 256) {
    float s2 = __fsub_rn(__fmul_rn((float)k + 0.5f, 256.0f / 513.0f), 0.5f);
    s2 = fminf(fmaxf(s2, 0.0f), 255.0f);
    int a0 = (int)s2;
    int a1 = min(a0 + 1, 255);
    float w2 = s2 - (float)a0;
    float u2 = d2[a0] * (1.0f - w2) + d2[a1] * w2;

    float s3 = __fsub_rn(__fmul_rn((float)k + 0.5f, 171.0f / 513.0f), 0.5f);
    s3 = fminf(fmaxf(s3, 0.0f), 170.0f);
    int c0 = (int)s3;
    int c1 = min(c0 + 1, 170);
    float w3 = s3 - (float)c0;
    float u3 = d3[c0] * (1.0f - w3) + d3[c1] * w3;

    float hs = log1pf(mags[k]) + log1pf(u2) + log1pf(u3);
    phm[k] = expm1f(hs);
  }
}

// -------- transpose channel c: chunk (b*6+c+1) (t,f) -> chunk (b*6+c) (f,t) --------
__global__ __launch_bounds__(256) void k_transpose(float* __restrict__ out, int c) {
  __shared__ float tile[64][65];
  const int t0 = blockIdx.x * 64;
  const int f0 = blockIdx.y * 64;
  const int b = blockIdx.z;
  const float* src = out + ((size_t)b * 6 + (c + 1)) * kFT;
  float* dst = out + ((size_t)b * 6 + c) * kFT;
  for (int i = threadIdx.x; i < 4096; i += 256) {
    int tl = i >> 6, fl = i & 63;
    int t = t0 + tl, f = f0 + fl;
    float v = 0.0f;
    if (t < kNT && f < kNF) v = src[(size_t)t * kNF + f];
    tile[fl][tl] = v;
  }
  __syncthreads();
  for (int i = threadIdx.x; i < 4096; i += 256) {
    int fl = i >> 6, tl = i & 63;
    int t = t0 + tl, f = f0 + fl;
    if (t < kNT && f < kNF)
      dst[(size_t)f * kNT + t] = tile[fl][tl];
  }
}

// -------- spread matrix, bf16, [576][544] zero-padded: Sb at ws + kDbBytes --------
__global__ __launch_bounds__(256) void k_spread(ushort* __restrict__ Sb) {
  const int f = blockIdx.x;   // 0..575
  const int tid = threadIdx.x;
  ushort* rowp = Sb + (size_t)f * kKP;
  if (f >= kNF) {             // pad rows: zeros
    for (int g = tid; g < kKP; g += 256) rowp[g] = 0;
    return;
  }
  __shared__ float bark[kNF];
  __shared__ float rowv[kNF];
  __shared__ float red[256];
  for (int g = tid; g < kNF; g += 256) {
    float fr = (float)g * (11025.0f / 512.0f);
    float r = fr * (1.0f / 7500.0f);
    bark[g] = 13.0f * atanf(0.00076f * fr) + 3.5f * atanf(r * r);
  }
  __syncthreads();
  float bf = bark[f];
  float partial = 0.0f;
  for (int g = tid; g < kNF; g += 256) {
    float d = fabsf(bf - bark[g]);
    float v = expf(-2.8f * d * d);   // == exp(-0.7*(d/0.5)^2); both ==1 at d==0
    rowv[g] = v;
    partial += v;
  }
  red[tid] = partial;
  __syncthreads();
  for (int off = 128; off > 0; off >>= 1) {
    if (tid < off) red[tid] += red[tid + off];
    __syncthreads();
  }
  float inv = 1.0f / (red[0] + 1e-8f);
  for (int g = tid; g < kNF; g += 256) rowp[g] = f2bf(rowv[g] * inv);
  for (int g = kNF + tid; g < kKP; g += 256) rowp[g] = 0;
}

// ------- masking GEMM via MFMA: out ch5 = clip(Sb @ Db^T - 0.12, 0, 1) -------
// A = Sb (M=f x K=g), B[g][t] = Db[t][g]. 16x16x32 bf16 MFMA.
// Layout (m89-verified): A: lane&15 = row, k = (lane>>4)*8+j (contiguous)
//                        B: lane&15 = col, same k          (contiguous)
//                        D: col = lane&15, row = (lane>>4)*4 + reg
__global__ __launch_bounds__(256) void k_psy(const ushort* __restrict__ Sb,
                                             const ushort* __restrict__ Db,
                                             float* __restrict__ out) {
  const int tid = threadIdx.x;
  const int w = tid >> 6;          // wave 0..3 -> f sub-tile
  const int l = tid & 63;
  const int lr = l & 15;
  const int lk = (l >> 4) * 8;
  const int f0 = blockIdx.y * 64 + w * 16;
  const int t0 = blockIdx.x * 64;
  const int b = blockIdx.z;

  const ushort* ap = Sb + (size_t)(f0 + lr) * kKP + lk;
  const size_t dbase = (size_t)b * kNT;
  const ushort* bp0 = Db + (dbase + min(t0 + lr,      kNT - 1)) * kKP + lk;
  const ushort* bp1 = Db + (dbase + min(t0 + lr + 16, kNT - 1)) * kKP + lk;
  const ushort* bp2 = Db + (dbase + min(t0 + lr + 32, kNT - 1)) * kKP + lk;
  const ushort* bp3 = Db + (dbase + min(t0 + lr + 48, kNT - 1)) * kKP + lk;

  f32x4 acc0 = {0.f, 0.f, 0.f, 0.f};
  f32x4 acc1 = {0.f, 0.f, 0.f, 0.f};
  f32x4 acc2 = {0.f, 0.f, 0.f, 0.f};
  f32x4 acc3 = {0.f, 0.f, 0.f, 0.f};
#pragma unroll 1
  for (int g0 = 0; g0 < kKP; g0 += 32) {
    bf16x8 a  = *(const bf16x8*)ap;  ap  += 32;
    bf16x8 b0 = *(const bf16x8*)bp0; bp0 += 32;
    bf16x8 b1 = *(const bf16x8*)bp1; bp1 += 32;
    bf16x8 b2 = *(const bf16x8*)bp2; bp2 += 32;
    bf16x8 b3 = *(const bf16x8*)bp3; bp3 += 32;
    acc0 = __builtin_amdgcn_mfma_f32_16x16x32_bf16(a, b0, acc0, 0, 0, 0);
    acc1 = __builtin_amdgcn_mfma_f32_16x16x32_bf16(a, b1, acc1, 0, 0, 0);
    acc2 = __builtin_amdgcn_mfma_f32_16x16x32_bf16(a, b2, acc2, 0, 0, 0);
    acc3 = __builtin_amdgcn_mfma_f32_16x16x32_bf16(a, b3, acc3, 0, 0, 0);
  }

  float* o5 = out + ((size_t)b * 6 + 5) * kFT;
  const int frow = f0 + (l >> 4) * 4;
  const int tcol = t0 + lr;
#pragma unroll
  for (int r = 0; r < 4; ++r) {
    int f = frow + r;
    if (f >= kNF) break;
    float vs[4] = {acc0[r], acc1[r], acc2[r], acc3[r]};
#pragma unroll
    for (int tt = 0; tt < 4; ++tt) {
      int t = tcol + 16 * tt;
      if (t < kNT) {
        float v = vs[tt] - 0.12f;
        v = fminf(fmaxf(v, 0.0f), 1.0f);
        o5[(size_t)f * kNT + t] = v;
      }
    }
  }
}

}  // namespace

extern "C" void kernel_launch(void* const* d_in, const int* in_sizes, int n_in,
                              void* d_out, int out_size, void* d_ws, size_t ws_size,
                              hipStream_t stream) {
  const float* x = (const float*)d_in[0];
  float* out = (float*)d_out;
  ushort* Db = (ushort*)d_ws;
  ushort* Sb = (ushort*)((char*)d_ws + kDbBytes);
  float* cst = (float*)((char*)d_ws + kCstBytes);

  // constant tables (twiddles + window)
  hipLaunchKernelGGL(k_const, dim3(1), dim3(256), 0, stream, cst);
  // spread matrix (bf16, padded) — independent of STFT
  hipLaunchKernelGGL(k_spread, dim3(kFP), dim3(256), 0, stream, Sb);
  // STFT + features: stage ch c at chunk (b*6+c+1); mag_db bf16 rows in Db
  hipLaunchKernelGGL(k_stft, dim3(kNT, kB), dim3(256), 0, stream, x, out, Db, cst);
  // transpose chain: launch c reads residue-(c+1) chunks, writes residue-c.
  for (int c = 0; c < 5; ++c) {
    hipLaunchKernelGGL(k_transpose, dim3((kNT + 63) / 64, (kNF + 63) / 64, kB),
                       dim3(256), 0, stream, out, c);
  }
  // masking GEMM (MFMA) -> channel 5 (reads Sb/Db, writes residue-5 chunks)
  hipLaunchKernelGGL(k_psy, dim3((kNT + 63) / 64, (kFP + 63) / 64, kB),
                     dim3(256), 0, stream, Sb, Db, out);
}

// Round 9
// 572.990 us; speedup vs baseline: 1.5105x; 1.1474x over previous
//
#include <hip/hip_runtime.h>
#include <math.h>

namespace {

constexpr int kB   = 8;
constexpr int kT   = 661500;   // input samples per channel
constexpr int kHop = 256;
constexpr int kNF  = 513;      // freq bins
constexpr int kNT  = 2584;     // frames
constexpr int kKP  = 544;      // K padded to 17*32 for MFMA
constexpr int kFP  = 576;      // f padded to 9*64 for MFMA A-tiles
constexpr size_t kFT = (size_t)kNF * kNT;   // floats per (b,c) output chunk

// ws: Db bf16 [8][2584][544] | Sb bf16 [576][544] | cst f32 twr512,twi512,win1024
constexpr size_t kDbBytes  = (size_t)kB * kNT * kKP * 2;
constexpr size_t kSbBytes  = (size_t)kFP * kKP * 2;
constexpr size_t kCstBytes = kDbBytes + kSbBytes;
typedef __attribute__((ext_vector_type(8))) short bf16x8;
typedef __attribute__((ext_vector_type(4))) float f32x4;

// Conflict-free LDS swizzle: bank kernel {e0+e2+e4+e6, e1+e3+e5} covers all
// bits 0..6 -> every FFT stage / scatter / unpack is <=2-way (free).
__device__ __forceinline__ int swz(int i) { return i ^ (i >> 2); }

__device__ __forceinline__ ushort f2bf(float x) {  // RNE float->bf16
  unsigned u = __float_as_uint(x);
  return (ushort)((u + 0x7FFFu + ((u >> 16) & 1u)) >> 16);
}
__device__ __forceinline__ float bf2f(ushort u) {
  return __uint_as_float((unsigned)u << 16);
}

// fast atan2: poly max err ~1e-6 rad (abs tolerance 2764 >> this)
__device__ __forceinline__ float fatan2(float y, float x) {
  float ax = fabsf(x), ay = fabsf(y);
  float mx = fmaxf(ax, ay), mn = fminf(ax, ay);
  float a = mn * __frcp_rn(fmaxf(mx, 1e-38f));
  float s = a * a;
  float r = fmaf(s, fmaf(s, fmaf(s, fmaf(s, fmaf(s, -0.0117212f, 0.05265332f),
            -0.11643287f), 0.19354346f), -0.33262347f), 0.99997726f) * a;
  if (ay > ax) r = 1.57079632679f - r;
  if (x < 0.0f) r = 3.14159265359f - r;
  return copysignf(r, y);
}

// ---------------- constant tables (twiddles + hann window) ----------------
__global__ __launch_bounds__(256) void k_const(float* __restrict__ cst) {
  const int tid = threadIdx.x;
  for (int j = tid; j < 512; j += 256) {   // exp(-2*pi*i*j/1024)
    float s, c;
    sincospif((float)j * (1.0f / 512.0f), &s, &c);
    cst[j] = c;
    cst[512 + j] = -s;
  }
  const float c2pi = 6.28318548202514648f;  // fl(2*pi), matches jnp fp32
  for (int n = tid; n < 1024; n += 256) {
    float arg = ((float)n * c2pi) * (1.0f / 1024.0f);
    cst[1024 + n] = 0.5f * (1.0f - cosf(arg));
  }
}

// ---------------- STFT + per-frame features ----------------
__global__ __launch_bounds__(256) void k_stft(const float* __restrict__ x,
                                              float* __restrict__ out,
                                              ushort* __restrict__ Db,
                                              const float* __restrict__ cst) {
  const int t = blockIdx.x;
  const int b = blockIdx.y;
  const int tid = threadIdx.x;
  __shared__ float sre[1024];
  __shared__ float sim[1024];
  __shared__ float twr[512];
  __shared__ float twi[512];
  __shared__ float mags[kNF];
  __shared__ float d2[256];
  __shared__ float d3[171];

  for (int j = tid; j < 512; j += 256) {
    twr[j] = cst[j];
    twi[j] = cst[512 + j];
  }

  const float* wtb = cst + 1024;
  const float* xb = x + (size_t)b * 2 * kT;
  const int start = t * kHop - 512;
  if (t >= 2 && t <= 2581) {   // fully interior: start>=0 AND start+1023<kT
    const float4 l4 = ((const float4*)(xb + start))[tid];
    const float4 r4 = ((const float4*)(xb + kT + start))[tid];
    const float4 w4 = ((const float4*)wtb)[tid];
    float lv[4] = {l4.x * w4.x, l4.y * w4.y, l4.z * w4.z, l4.w * w4.w};
    float rv_[4] = {r4.x * w4.x, r4.y * w4.y, r4.z * w4.z, r4.w * w4.w};
#pragma unroll
    for (int e = 0; e < 4; ++e) {
      int n = tid * 4 + e;
      int rs = swz((int)(__brev((unsigned)n) >> 22));
      sre[rs] = lv[e];
      sim[rs] = rv_[e];
    }
  } else {                      // edge frames: t in {0,1,2582,2583}
#pragma unroll
    for (int q = 0; q < 4; ++q) {
      int n = tid + q * 256;
      int g = start + n;
      g = (g < 0) ? -g : g;
      g = (g >= kT) ? (2 * kT - 2 - g) : g;
      float wv = wtb[n];
      int rs = swz((int)(__brev((unsigned)n) >> 22));
      sre[rs] = xb[g] * wv;
      sim[rs] = xb[(size_t)kT + g] * wv;
    }
  }

  // 5 fused double-radix-2 passes (stages 2p+1, 2p+2)
#pragma unroll
  for (int p = 0; p < 5; ++p) {
    __syncthreads();
    const int half = 1 << (2 * p);
    const int c1 = swz(half), c2s = swz(2 * half), c3s = swz(3 * half);
    const int pos = tid & (half - 1);
    const int i0 = ((tid >> (2 * p)) << (2 * p + 2)) + pos;
    const int a0 = swz(i0), a1 = a0 ^ c1, a2 = a0 ^ c2s, a3 = a0 ^ c3s;
    const int ti1 = pos << (9 - 2 * p);
    const int ti2 = pos << (8 - 2 * p);
    float w1r = twr[ti1], w1i = twi[ti1];
    float w2r = twr[ti2], w2i = twi[ti2];
    float e0r = sre[a0], e0i = sim[a0];
    float e1r = sre[a1], e1i = sim[a1];
    float e2r = sre[a2], e2i = sim[a2];
    float e3r = sre[a3], e3i = sim[a3];
    // stage s: (e0,e1),(e2,e3) with w1
    float t1r = e1r * w1r - e1i * w1i, t1i = e1r * w1i + e1i * w1r;
    float t3r = e3r * w1r - e3i * w1i, t3i = e3r * w1i + e3i * w1r;
    float u0r = e0r + t1r, u0i = e0i + t1i;
    float u1r = e0r - t1r, u1i = e0i - t1i;
    float u2r = e2r + t3r, u2i = e2i + t3i;
    float u3r = e2r - t3r, u3i = e2i - t3i;
    // stage s+1: (u0,u2) with w2; (u1,u3) with -i*w2
    float q2r = u2r * w2r - u2i * w2i, q2i = u2r * w2i + u2i * w2r;
    float q3r = u3r * w2r - u3i * w2i, q3i = u3r * w2i + u3i * w2r;
    sre[a0] = u0r + q2r; sim[a0] = u0i + q2i;
    sre[a2] = u0r - q2r; sim[a2] = u0i - q2i;
    sre[a1] = u1r + q3i; sim[a1] = u1i - q3r;
    sre[a3] = u1r - q3i; sim[a3] = u1i + q3r;
  }
  __syncthreads();

  // staging (bf16, two planes per out chunk): ch0,1 -> chunk b*6+2;
  // ch2,3 -> chunk b*6+4; ch4 -> chunk b*6+5. (t,f) layout.
  ushort* outU = (ushort*)out;
  const size_t c2o = ((size_t)b * 6 + 2) * (2 * kFT);
  const size_t c4o = ((size_t)b * 6 + 4) * (2 * kFT);
  const size_t c5o = ((size_t)b * 6 + 5) * (2 * kFT);
  const size_t row = (size_t)t * kNF;
  ushort* pre = outU + c2o + row;          // ch0 re
  ushort* pim = outU + c2o + kFT + row;    // ch1 im
  ushort* phm = outU + c4o + row;          // ch2 harm
  ushort* pip = outU + c4o + kFT + row;    // ch3 ipd
  ushort* ppn = outU + c5o + row;          // ch4 pan
  ushort* pdb = Db + ((size_t)b * kNT + t) * kKP;

  for (int k = tid; k < kNF; k += 256) {
    int k2 = (1024 - k) & 1023;
    float a = sre[swz(k)], bb = sim[swz(k)];
    float c = sre[swz(k2)], d = sim[swz(k2)];
    float Lre = 0.5f * (a + c), Lim = 0.5f * (bb - d);
    float Rre = 0.5f * (bb + d), Rim = 0.5f * (c - a);
    float sr = 0.5f * (Lre + Rre), si = 0.5f * (Lim + Rim);
    float mg = sqrtf(sr * sr + si * si);
    mags[k] = mg;
    float ipd = fatan2(Lim, Lre) - fatan2(Rim, Rre);
    float el = Lre * Lre + Lim * Lim;
    float er = Rre * Rre + Rim * Rim;
    float pan = (el - er) * __frcp_rn(el + er + 1e-10f);
    float mm = fmaxf(mg, 1e-10f);
    float db = 6.02059991328f * __log2f(mm);   // 20*log10(m)
    db = fminf(fmaxf(db, -100.0f), 0.0f);
    pre[k] = f2bf(sr);
    pim[k] = f2bf(si);
    pip[k] = f2bf(ipd);
    ppn[k] = f2bf(pan);
    pdb[k] = f2bf((db + 100.0f) * 0.01f);
  }
  for (int k = kNF + tid; k < kKP; k += 256) pdb[k] = 0;
  __syncthreads();

  // harmonic: downsample to 256 and 171 (reference arithmetic)
  {
    int j = tid;
    float src = __fsub_rn(__fmul_rn((float)j + 0.5f, 513.0f / 256.0f), 0.5f);
    src = fminf(fmaxf(src, 0.0f), 512.0f);
    int i0 = (int)src;
    int i1 = min(i0 + 1, 512);
    float w = src - (float)i0;
    d2[j] = mags[i0] * (1.0f - w) + mags[i1] * w;
  }
  if (tid < 171) {
    int j = tid;
    float src = __fsub_rn(__fmul_rn((float)j + 0.5f, 3.0f), 0.5f);
    src = fminf(fmaxf(src, 0.0f), 512.0f);
    int i0 = (int)src;
    int i1 = min(i0 + 1, 512);
    float w = src - (float)i0;
    d3[j] = mags[i0] * (1.0f - w) + mags[i1] * w;
  }
  __syncthreads();

  // upsample back; exact product form of expm1(sum log1p) (err << tol)
  for (int k = tid; k < kNF; k += 256) {
    float s2 = __fsub_rn(__fmul_rn((float)k + 0.5f, 256.0f / 513.0f), 0.5f);
    s2 = fminf(fmaxf(s2, 0.0f), 255.0f);
    int a0 = (int)s2;
    int a1 = min(a0 + 1, 255);
    float w2 = s2 - (float)a0;
    float u2 = d2[a0] * (1.0f - w2) + d2[a1] * w2;

    float s3 = __fsub_rn(__fmul_rn((float)k + 0.5f, 171.0f / 513.0f), 0.5f);
    s3 = fminf(fmaxf(s3, 0.0f), 170.0f);
    int c0 = (int)s3;
    int c1 = min(c0 + 1, 170);
    float w3 = s3 - (float)c0;
    float u3 = d3[c0] * (1.0f - w3) + d3[c1] * w3;

    float hp = (1.0f + mags[k]) * (1.0f + u2) * (1.0f + u3) - 1.0f;
    phm[k] = f2bf(hp);
  }
}

// ---- transpose nch channels: bf16 staging (src_res chunk) -> fp32 (f,t) ----
__global__ __launch_bounds__(256) void k_transpose(float* __restrict__ out,
                                                   int src_res, int dst_res0,
                                                   int nch) {
  __shared__ float tile[64][65];
  const int t0 = blockIdx.x * 64;
  const int f0 = blockIdx.y * 64;
  const int b = blockIdx.z;
  const ushort* sbase = (const ushort*)(out + ((size_t)b * 6 + src_res) * kFT);
  for (int cc = 0; cc < nch; ++cc) {
    const ushort* sp = sbase + (size_t)cc * kFT;
    float* dst = out + ((size_t)b * 6 + dst_res0 + cc) * kFT;
    for (int i = threadIdx.x; i < 4096; i += 256) {
      int tl = i >> 6, fl = i & 63;
      int t = t0 + tl, f = f0 + fl;
      float v = 0.0f;
      if (t < kNT && f < kNF) v = bf2f(sp[(size_t)t * kNF + f]);
      tile[fl][tl] = v;
    }
    __syncthreads();
    for (int i = threadIdx.x; i < 4096; i += 256) {
      int fl = i >> 6, tl = i & 63;
      int t = t0 + tl, f = f0 + fl;
      if (t < kNT && f < kNF)
        dst[(size_t)f * kNT + t] = tile[fl][tl];
    }
    __syncthreads();
  }
}

// -------- spread matrix, bf16, [576][544] zero-padded --------
__global__ __launch_bounds__(256) void k_spread(ushort* __restrict__ Sb) {
  const int f = blockIdx.x;   // 0..575
  const int tid = threadIdx.x;
  ushort* rowp = Sb + (size_t)f * kKP;
  if (f >= kNF) {
    for (int g = tid; g < kKP; g += 256) rowp[g] = 0;
    return;
  }
  __shared__ float bark[kNF];
  __shared__ float rowv[kNF];
  __shared__ float red[256];
  for (int g = tid; g < kNF; g += 256) {
    float fr = (float)g * (11025.0f / 512.0f);
    float r = fr * (1.0f / 7500.0f);
    bark[g] = 13.0f * atanf(0.00076f * fr) + 3.5f * atanf(r * r);
  }
  __syncthreads();
  float bf = bark[f];
  float partial = 0.0f;
  for (int g = tid; g < kNF; g += 256) {
    float d = fabsf(bf - bark[g]);
    float v = expf(-2.8f * d * d);
    rowv[g] = v;
    partial += v;
  }
  red[tid] = partial;
  __syncthreads();
  for (int off = 128; off > 0; off >>= 1) {
    if (tid < off) red[tid] += red[tid + off];
    __syncthreads();
  }
  float inv = 1.0f / (red[0] + 1e-8f);
  for (int g = tid; g < kNF; g += 256) rowp[g] = f2bf(rowv[g] * inv);
  for (int g = kNF + tid; g < kKP; g += 256) rowp[g] = 0;
}

// ------- masking GEMM via MFMA: waves own t-subtiles (Db loaded once/block) -------
__global__ __launch_bounds__(256) void k_psy(const ushort* __restrict__ Sb,
                                             const ushort* __restrict__ Db,
                                             float* __restrict__ out) {
  const int tid = threadIdx.x;
  const int w = tid >> 6;
  const int l = tid & 63;
  const int lr = l & 15;
  const int lk = (l >> 4) * 8;
  const int f0 = blockIdx.y * 64;
  const int t0 = blockIdx.x * 64 + w * 16;
  const int b = blockIdx.z;

  const ushort* ap = Sb + (size_t)(f0 + lr) * kKP + lk;
  const ushort* bp = Db + ((size_t)b * kNT + min(t0 + lr, kNT - 1)) * kKP + lk;

  f32x4 acc0 = {0.f, 0.f, 0.f, 0.f};
  f32x4 acc1 = {0.f, 0.f, 0.f, 0.f};
  f32x4 acc2 = {0.f, 0.f, 0.f, 0.f};
  f32x4 acc3 = {0.f, 0.f, 0.f, 0.f};
#pragma unroll 1
  for (int g0 = 0; g0 < kKP; g0 += 32) {
    bf16x8 bb = *(const bf16x8*)bp; bp += 32;
    bf16x8 a0 = *(const bf16x8*)(ap);
    bf16x8 a1 = *(const bf16x8*)(ap + 16 * kKP);
    bf16x8 a2 = *(const bf16x8*)(ap + 32 * kKP);
    bf16x8 a3 = *(const bf16x8*)(ap + 48 * kKP);
    ap += 32;
    acc0 = __builtin_amdgcn_mfma_f32_16x16x32_bf16(a0, bb, acc0, 0, 0, 0);
    acc1 = __builtin_amdgcn_mfma_f32_16x16x32_bf16(a1, bb, acc1, 0, 0, 0);
    acc2 = __builtin_amdgcn_mfma_f32_16x16x32_bf16(a2, bb, acc2, 0, 0, 0);
    acc3 = __builtin_amdgcn_mfma_f32_16x16x32_bf16(a3, bb, acc3, 0, 0, 0);
  }

  float* o5 = out + ((size_t)b * 6 + 5) * kFT;
  const int tcol = t0 + lr;
  const int fbase = f0 + (l >> 4) * 4;
  if (tcol < kNT) {
    const f32x4 accs[4] = {acc0, acc1, acc2, acc3};
#pragma unroll
    for (int ff = 0; ff < 4; ++ff) {
#pragma unroll
      for (int r = 0; r < 4; ++r) {
        int f = fbase + ff * 16 + r;
        if (f < kNF) {
          float v = accs[ff][r] - 0.12f;
          v = fminf(fmaxf(v, 0.0f), 1.0f);
          o5[(size_t)f * kNT + tcol] = v;
        }
      }
    }
  }
}

}  // namespace

extern "C" void kernel_launch(void* const* d_in, const int* in_sizes, int n_in,
                              void* d_out, int out_size, void* d_ws, size_t ws_size,
                              hipStream_t stream) {
  const float* x = (const float*)d_in[0];
  float* out = (float*)d_out;
  ushort* Db = (ushort*)d_ws;
  ushort* Sb = (ushort*)((char*)d_ws + kDbBytes);
  float* cst = (float*)((char*)d_ws + kCstBytes);

  hipLaunchKernelGGL(k_const, dim3(1), dim3(256), 0, stream, cst);
  hipLaunchKernelGGL(k_spread, dim3(kFP), dim3(256), 0, stream, Sb);
  hipLaunchKernelGGL(k_stft, dim3(kNT, kB), dim3(256), 0, stream, x, out, Db, cst);
  // transpose chain (race-free via stream order):
  //   A: residues {0,1} <- staging@2 ; B: {2,3} <- staging@4 ; C: {4} <- staging@5
  hipLaunchKernelGGL(k_transpose, dim3((kNT + 63) / 64, (kNF + 63) / 64, kB),
                     dim3(256), 0, stream, out, 2, 0, 2);
  hipLaunchKernelGGL(k_transpose, dim3((kNT + 63) / 64, (kNF + 63) / 64, kB),
                     dim3(256), 0, stream, out, 4, 2, 2);
  hipLaunchKernelGGL(k_transpose, dim3((kNT + 63) / 64, (kNF + 63) / 64, kB),
                     dim3(256), 0, stream, out, 5, 4, 1);
  // masking GEMM -> channel 5 (after C consumed staging@5)
  hipLaunchKernelGGL(k_psy, dim3((kNT + 63) / 64, (kFP + 63) / 64, kB),
                     dim3(256), 0, stream, Sb, Db, out);
}

// Round 11
// 546.671 us; speedup vs baseline: 1.5833x; 1.0481x over previous
//
#include <hip/hip_runtime.h>
#include <math.h>

namespace {

constexpr int kB   = 8;
constexpr int kT   = 661500;   // input samples per channel
constexpr int kHop = 256;
constexpr int kNF  = 513;      // freq bins
constexpr int kNT  = 2584;     // frames
constexpr int kKP  = 544;      // K padded to 17*32 for MFMA
constexpr int kFP  = 576;      // f padded to 9*64 for MFMA A-tiles
constexpr size_t kFT = (size_t)kNF * kNT;   // floats per (b,c) output chunk

// ws: Db bf16 [8][2584][544] | Sb bf16 [576][544] | cst f32 twr512,twi512,win1024
constexpr size_t kDbBytes  = (size_t)kB * kNT * kKP * 2;
constexpr size_t kSbBytes  = (size_t)kFP * kKP * 2;
constexpr size_t kCstBytes = kDbBytes + kSbBytes;
typedef __attribute__((ext_vector_type(8))) short bf16x8;
typedef __attribute__((ext_vector_type(4))) float f32x4;

// Conflict-free LDS swizzle: bank kernel {e0+e2+e4+e6, e1+e3+e5} covers all
// bits 0..6 -> every FFT stage / scatter / unpack is <=2-way (free).
__device__ __forceinline__ int swz(int i) { return i ^ (i >> 2); }

__device__ __forceinline__ ushort f2bf(float x) {  // RNE float->bf16
  unsigned u = __float_as_uint(x);
  return (ushort)((u + 0x7FFFu + ((u >> 16) & 1u)) >> 16);
}
__device__ __forceinline__ float bf2f(ushort u) {
  return __uint_as_float((unsigned)u << 16);
}
__device__ __forceinline__ unsigned pack2(float lo, float hi) {
  return (unsigned)f2bf(lo) | ((unsigned)f2bf(hi) << 16);
}

// fast atan2: poly max err ~1e-6 rad (abs tolerance 2764 >> this)
__device__ __forceinline__ float fatan2(float y, float x) {
  float ax = fabsf(x), ay = fabsf(y);
  float mx = fmaxf(ax, ay), mn = fminf(ax, ay);
  float a = mn * __frcp_rn(fmaxf(mx, 1e-38f));
  float s = a * a;
  float r = fmaf(s, fmaf(s, fmaf(s, fmaf(s, fmaf(s, -0.0117212f, 0.05265332f),
            -0.11643287f), 0.19354346f), -0.33262347f), 0.99997726f) * a;
  if (ay > ax) r = 1.57079632679f - r;
  if (x < 0.0f) r = 3.14159265359f - r;
  return copysignf(r, y);
}

// ---- spread matrix bf16 [576][544] (blocks 0..575) + const tables (block 576) ----
__global__ __launch_bounds__(256) void k_spread(ushort* __restrict__ Sb,
                                                float* __restrict__ cst) {
  const int f = blockIdx.x;   // 0..576
  const int tid = threadIdx.x;
  if (f == kFP) {             // constant tables: twiddles + hann window
    for (int j = tid; j < 512; j += 256) {
      float s, c;
      sincospif((float)j * (1.0f / 512.0f), &s, &c);
      cst[j] = c;
      cst[512 + j] = -s;
    }
    const float c2pi = 6.28318548202514648f;  // fl(2*pi), matches jnp fp32
    for (int n = tid; n < 1024; n += 256) {
      float arg = ((float)n * c2pi) * (1.0f / 1024.0f);
      cst[1024 + n] = 0.5f * (1.0f - cosf(arg));
    }
    return;
  }
  ushort* rowp = Sb + (size_t)f * kKP;
  if (f >= kNF) {
    for (int g = tid; g < kKP; g += 256) rowp[g] = 0;
    return;
  }
  __shared__ float bark[kNF];
  __shared__ float rowv[kNF];
  __shared__ float red[256];
  for (int g = tid; g < kNF; g += 256) {
    float fr = (float)g * (11025.0f / 512.0f);
    float r = fr * (1.0f / 7500.0f);
    bark[g] = 13.0f * atanf(0.00076f * fr) + 3.5f * atanf(r * r);
  }
  __syncthreads();
  float bf = bark[f];
  float partial = 0.0f;
  for (int g = tid; g < kNF; g += 256) {
    float d = fabsf(bf - bark[g]);
    float v = expf(-2.8f * d * d);
    rowv[g] = v;
    partial += v;
  }
  red[tid] = partial;
  __syncthreads();
  for (int off = 128; off > 0; off >>= 1) {
    if (tid < off) red[tid] += red[tid + off];
    __syncthreads();
  }
  float inv = 1.0f / (red[0] + 1e-8f);
  for (int g = tid; g < kNF; g += 256) rowp[g] = f2bf(rowv[g] * inv);
  for (int g = kNF + tid; g < kKP; g += 256) rowp[g] = 0;
}

// ---------------- STFT + per-frame features ----------------
// Staging (all (t,f) layout, inside d_out):
//   chunk b*6+2 as u32: lo=re(ch0), hi=im(ch1)
//   chunk b*6+4 as u32: lo=harm(ch2), hi=ipd(ch3)
//   chunk b*6+5 as bf16 (first kFT ushorts): pan(ch4)
__global__ __launch_bounds__(256) void k_stft(const float* __restrict__ x,
                                              float* __restrict__ out,
                                              ushort* __restrict__ Db,
                                              const float* __restrict__ cst) {
  const int t = blockIdx.x;
  const int b = blockIdx.y;
  const int tid = threadIdx.x;
  __shared__ float sre[1024];
  __shared__ float sim[1024];
  __shared__ float twr[512];
  __shared__ float twi[512];
  __shared__ float mags[kNF];
  __shared__ float d2[256];
  __shared__ float d3[171];

  for (int j = tid; j < 512; j += 256) {
    twr[j] = cst[j];
    twi[j] = cst[512 + j];
  }

  const float* wtb = cst + 1024;
  const float* xb = x + (size_t)b * 2 * kT;
  const int start = t * kHop - 512;
  if (t >= 2 && t <= 2581) {   // fully interior: start>=0 AND start+1023<kT
    const float4 l4 = ((const float4*)(xb + start))[tid];
    const float4 r4 = ((const float4*)(xb + kT + start))[tid];
    const float4 w4 = ((const float4*)wtb)[tid];
    float lv[4] = {l4.x * w4.x, l4.y * w4.y, l4.z * w4.z, l4.w * w4.w};
    float rv_[4] = {r4.x * w4.x, r4.y * w4.y, r4.z * w4.z, r4.w * w4.w};
#pragma unroll
    for (int e = 0; e < 4; ++e) {
      int n = tid * 4 + e;
      int rs = swz((int)(__brev((unsigned)n) >> 22));
      sre[rs] = lv[e];
      sim[rs] = rv_[e];
    }
  } else {                      // edge frames: t in {0,1,2582,2583}
#pragma unroll
    for (int q = 0; q < 4; ++q) {
      int n = tid + q * 256;
      int g = start + n;
      g = (g < 0) ? -g : g;
      g = (g >= kT) ? (2 * kT - 2 - g) : g;
      float wv = wtb[n];
      int rs = swz((int)(__brev((unsigned)n) >> 22));
      sre[rs] = xb[g] * wv;
      sim[rs] = xb[(size_t)kT + g] * wv;
    }
  }

  // 5 fused double-radix-2 passes (stages 2p+1, 2p+2)
#pragma unroll
  for (int p = 0; p < 5; ++p) {
    __syncthreads();
    const int half = 1 << (2 * p);
    const int c1 = swz(half), c2s = swz(2 * half), c3s = swz(3 * half);
    const int pos = tid & (half - 1);
    const int i0 = ((tid >> (2 * p)) << (2 * p + 2)) + pos;
    const int a0 = swz(i0), a1 = a0 ^ c1, a2 = a0 ^ c2s, a3 = a0 ^ c3s;
    const int ti1 = pos << (9 - 2 * p);
    const int ti2 = pos << (8 - 2 * p);
    float w1r = twr[ti1], w1i = twi[ti1];
    float w2r = twr[ti2], w2i = twi[ti2];
    float e0r = sre[a0], e0i = sim[a0];
    float e1r = sre[a1], e1i = sim[a1];
    float e2r = sre[a2], e2i = sim[a2];
    float e3r = sre[a3], e3i = sim[a3];
    // stage s: (e0,e1),(e2,e3) with w1
    float t1r = e1r * w1r - e1i * w1i, t1i = e1r * w1i + e1i * w1r;
    float t3r = e3r * w1r - e3i * w1i, t3i = e3r * w1i + e3i * w1r;
    float u0r = e0r + t1r, u0i = e0i + t1i;
    float u1r = e0r - t1r, u1i = e0i - t1i;
    float u2r = e2r + t3r, u2i = e2i + t3i;
    float u3r = e2r - t3r, u3i = e2i - t3i;
    // stage s+1: (u0,u2) with w2; (u1,u3) with -i*w2
    float q2r = u2r * w2r - u2i * w2i, q2i = u2r * w2i + u2i * w2r;
    float q3r = u3r * w2r - u3i * w2i, q3i = u3r * w2i + u3i * w2r;
    sre[a0] = u0r + q2r; sim[a0] = u0i + q2i;
    sre[a2] = u0r - q2r; sim[a2] = u0i - q2i;
    sre[a1] = u1r + q3i; sim[a1] = u1i - q3r;
    sre[a3] = u1r - q3i; sim[a3] = u1i + q3r;
  }
  __syncthreads();

  unsigned* u32o = (unsigned*)out;
  unsigned* pri = u32o + ((size_t)b * 6 + 2) * kFT + (size_t)t * kNF;  // (re,im)
  unsigned* phi = u32o + ((size_t)b * 6 + 4) * kFT + (size_t)t * kNF;  // (harm,ipd)
  ushort* ppn = (ushort*)out + ((size_t)b * 6 + 5) * (2 * kFT) + (size_t)t * kNF;
  ushort* pdb = Db + ((size_t)b * kNT + t) * kKP;
  __shared__ float ipds[kNF];

  for (int k = tid; k < kNF; k += 256) {
    int k2 = (1024 - k) & 1023;
    float a = sre[swz(k)], bb = sim[swz(k)];
    float c = sre[swz(k2)], d = sim[swz(k2)];
    float Lre = 0.5f * (a + c), Lim = 0.5f * (bb - d);
    float Rre = 0.5f * (bb + d), Rim = 0.5f * (c - a);
    float sr = 0.5f * (Lre + Rre), si = 0.5f * (Lim + Rim);
    float mg = sqrtf(sr * sr + si * si);
    mags[k] = mg;
    float ipd = fatan2(Lim, Lre) - fatan2(Rim, Rre);
    ipds[k] = ipd;
    float el = Lre * Lre + Lim * Lim;
    float er = Rre * Rre + Rim * Rim;
    float pan = (el - er) * __frcp_rn(el + er + 1e-10f);
    float mm = fmaxf(mg, 1e-10f);
    float db = 6.02059991328f * __log2f(mm);   // 20*log10(m)
    db = fminf(fmaxf(db, -100.0f), 0.0f);
    pri[k] = pack2(sr, si);
    ppn[k] = f2bf(pan);
    pdb[k] = f2bf((db + 100.0f) * 0.01f);
  }
  for (int k = kNF + tid; k < kKP; k += 256) pdb[k] = 0;
  __syncthreads();

  // harmonic: downsample to 256 and 171 (reference arithmetic)
  {
    int j = tid;
    float src = __fsub_rn(__fmul_rn((float)j + 0.5f, 513.0f / 256.0f), 0.5f);
    src = fminf(fmaxf(src, 0.0f), 512.0f);
    int i0 = (int)src;
    int i1 = min(i0 + 1, 512);
    float w = src - (float)i0;
    d2[j] = mags[i0] * (1.0f - w) + mags[i1] * w;
  }
  if (tid < 171) {
    int j = tid;
    float src = __fsub_rn(__fmul_rn((float)j + 0.5f, 3.0f), 0.5f);
    src = fminf(fmaxf(src, 0.0f), 512.0f);
    int i0 = (int)src;
    int i1 = min(i0 + 1, 512);
    float w = src - (float)i0;
    d3[j] = mags[i0] * (1.0f - w) + mags[i1] * w;
  }
  __syncthreads();

  // upsample back; exact product form of expm1(sum log1p) (err << tol)
  for (int k = tid; k < kNF; k += 256) {
    float s2 = __fsub_rn(__fmul_rn((float)k + 0.5f, 256.0f / 513.0f), 0.5f);
    s2 = fminf(fmaxf(s2, 0.0f), 255.0f);
    int a0 = (int)s2;
    int a1 = min(a0 + 1, 255);
    float w2 = s2 - (float)a0;
    float u2 = d2[a0] * (1.0f - w2) + d2[a1] * w2;

    float s3 = __fsub_rn(__fmul_rn((float)k + 0.5f, 171.0f / 513.0f), 0.5f);
    s3 = fminf(fmaxf(s3, 0.0f), 170.0f);
    int c0 = (int)s3;
    int c1 = min(c0 + 1, 170);
    float w3 = s3 - (float)c0;
    float u3 = d3[c0] * (1.0f - w3) + d3[c1] * w3;

    float hp = (1.0f + mags[k]) * (1.0f + u2) * (1.0f + u3) - 1.0f;
    phi[k] = pack2(hp, ipds[k]);
  }
}

// ---- transpose packed u32 staging (src_res) -> two fp32 (f,t) planes ----
__global__ __launch_bounds__(256) void k_transpose_pair(float* __restrict__ out,
                                                        int src_res, int dst_res0) {
  __shared__ unsigned tile[64][65];
  const int t0 = blockIdx.x * 64;
  const int f0 = blockIdx.y * 64;
  const int b = blockIdx.z;
  const unsigned* sp = (const unsigned*)out + ((size_t)b * 6 + src_res) * kFT;
  float* dst0 = out + ((size_t)b * 6 + dst_res0) * kFT;
  float* dst1 = out + ((size_t)b * 6 + dst_res0 + 1) * kFT;
  for (int i = threadIdx.x; i < 4096; i += 256) {
    int tl = i >> 6, fl = i & 63;
    int t = t0 + tl, f = f0 + fl;
    unsigned v = 0;
    if (t < kNT && f < kNF) v = sp[(size_t)t * kNF + f];
    tile[fl][tl] = v;
  }
  __syncthreads();
  for (int i = threadIdx.x; i < 4096; i += 256) {
    int fl = i >> 6, tl = i & 63;
    int t = t0 + tl, f = f0 + fl;
    if (t < kNT && f < kNF) {
      unsigned v = tile[fl][tl];
      size_t o = (size_t)f * kNT + t;
      dst0[o] = bf2f((ushort)(v & 0xFFFFu));
      dst1[o] = bf2f((ushort)(v >> 16));
    }
  }
}

// ---- transpose one bf16 plane (src_res chunk) -> fp32 (f,t) ----
__global__ __launch_bounds__(256) void k_transpose_one(float* __restrict__ out,
                                                       int src_res, int dst_res) {
  __shared__ float tile[64][65];
  const int t0 = blockIdx.x * 64;
  const int f0 = blockIdx.y * 64;
  const int b = blockIdx.z;
  const ushort* sp = (const ushort*)(out + ((size_t)b * 6 + src_res) * kFT);
  float* dst = out + ((size_t)b * 6 + dst_res) * kFT;
  for (int i = threadIdx.x; i < 4096; i += 256) {
    int tl = i >> 6, fl = i & 63;
    int t = t0 + tl, f = f0 + fl;
    float v = 0.0f;
    if (t < kNT && f < kNF) v = bf2f(sp[(size_t)t * kNF + f]);
    tile[fl][tl] = v;
  }
  __syncthreads();
  for (int i = threadIdx.x; i < 4096; i += 256) {
    int fl = i >> 6, tl = i & 63;
    int t = t0 + tl, f = f0 + fl;
    if (t < kNT && f < kNF)
      dst[(size_t)f * kNT + t] = tile[fl][tl];
  }
}

// ------- masking GEMM via MFMA: waves own t-subtiles (Db loaded once/block) -------
__global__ __launch_bounds__(256) void k_psy(const ushort* __restrict__ Sb,
                                             const ushort* __restrict__ Db,
                                             float* __restrict__ out) {
  const int tid = threadIdx.x;
  const int w = tid >> 6;
  const int l = tid & 63;
  const int lr = l & 15;
  const int lk = (l >> 4) * 8;
  const int f0 = blockIdx.y * 64;
  const int t0 = blockIdx.x * 64 + w * 16;
  const int b = blockIdx.z;

  const ushort* ap = Sb + (size_t)(f0 + lr) * kKP + lk;
  const ushort* bp = Db + ((size_t)b * kNT + min(t0 + lr, kNT - 1)) * kKP + lk;

  f32x4 acc0 = {0.f, 0.f, 0.f, 0.f};
  f32x4 acc1 = {0.f, 0.f, 0.f, 0.f};
  f32x4 acc2 = {0.f, 0.f, 0.f, 0.f};
  f32x4 acc3 = {0.f, 0.f, 0.f, 0.f};
#pragma unroll 1
  for (int g0 = 0; g0 < kKP; g0 += 32) {
    bf16x8 bb = *(const bf16x8*)bp; bp += 32;
    bf16x8 a0 = *(const bf16x8*)(ap);
    bf16x8 a1 = *(const bf16x8*)(ap + 16 * kKP);
    bf16x8 a2 = *(const bf16x8*)(ap + 32 * kKP);
    bf16x8 a3 = *(const bf16x8*)(ap + 48 * kKP);
    ap += 32;
    acc0 = __builtin_amdgcn_mfma_f32_16x16x32_bf16(a0, bb, acc0, 0, 0, 0);
    acc1 = __builtin_amdgcn_mfma_f32_16x16x32_bf16(a1, bb, acc1, 0, 0, 0);
    acc2 = __builtin_amdgcn_mfma_f32_16x16x32_bf16(a2, bb, acc2, 0, 0, 0);
    acc3 = __builtin_amdgcn_mfma_f32_16x16x32_bf16(a3, bb, acc3, 0, 0, 0);
  }

  float* o5 = out + ((size_t)b * 6 + 5) * kFT;
  const int tcol = t0 + lr;
  const int fbase = f0 + (l >> 4) * 4;
  if (tcol < kNT) {
    const f32x4 accs[4] = {acc0, acc1, acc2, acc3};
#pragma unroll
    for (int ff = 0; ff < 4; ++ff) {
#pragma unroll
      for (int r = 0; r < 4; ++r) {
        int f = fbase + ff * 16 + r;
        if (f < kNF) {
          float v = accs[ff][r] - 0.12f;
          v = fminf(fmaxf(v, 0.0f), 1.0f);
          o5[(size_t)f * kNT + tcol] = v;
        }
      }
    }
  }
}

}  // namespace

extern "C" void kernel_launch(void* const* d_in, const int* in_sizes, int n_in,
                              void* d_out, int out_size, void* d_ws, size_t ws_size,
                              hipStream_t stream) {
  const float* x = (const float*)d_in[0];
  float* out = (float*)d_out;
  ushort* Db = (ushort*)d_ws;
  ushort* Sb = (ushort*)((char*)d_ws + kDbBytes);
  float* cst = (float*)((char*)d_ws + kCstBytes);

  // spread matrix + constant tables (block 576)
  hipLaunchKernelGGL(k_spread, dim3(kFP + 1), dim3(256), 0, stream, Sb, cst);
  // STFT + features: packed staging @res2 (re,im), @res4 (harm,ipd), @res5 pan
  hipLaunchKernelGGL(k_stft, dim3(kNT, kB), dim3(256), 0, stream, x, out, Db, cst);
  // transpose chain (race-free via stream order):
  dim3 tg((kNT + 63) / 64, (kNF + 63) / 64, kB);
  hipLaunchKernelGGL(k_transpose_pair, tg, dim3(256), 0, stream, out, 2, 0);
  hipLaunchKernelGGL(k_transpose_pair, tg, dim3(256), 0, stream, out, 4, 2);
  hipLaunchKernelGGL(k_transpose_one,  tg, dim3(256), 0, stream, out, 5, 4);
  // masking GEMM -> channel 5 (after transpose_one consumed staging@5)
  hipLaunchKernelGGL(k_psy, dim3((kNT + 63) / 64, (kFP + 63) / 64, kB),
                     dim3(256), 0, stream, Sb, Db, out);
}